// Round 4
// baseline (47.884 us; speedup 1.0000x reference)
//
#include <hip/hip_runtime.h>

#define NB 64
#define NS 512
#define ND 768
#define NT 4
#define NC 10
#define VOCAB 21128
#define NEG (-1e30f)

// ---------------------------------------------------------------------------
// Kernel 0: build wt[t][d][c] = sW[d][t] + dA[c][d][t]  (4*768*10)
//           and beff[c][t] = sb[t] + db[c][t]
// t-major weight layout makes proj's per-k 10-float weight run contiguous
// and wave-uniform -> scalar loads.
// ---------------------------------------------------------------------------
__global__ void weff_kernel(const float* __restrict__ sW,
                            const float* __restrict__ dA,
                            const float* __restrict__ sb,
                            const float* __restrict__ db,
                            float* __restrict__ wt,
                            float* __restrict__ beff)
{
  const int i = blockIdx.x * 256 + threadIdx.x;
  if (i < NT * ND * NC) {
    const int t = i / (ND * NC);
    const int d = (i / NC) % ND;
    const int c = i % NC;
    wt[i] = sW[d * NT + t] + dA[(c * ND + d) * NT + t];
  }
  if (i < NC * NT) beff[i] = sb[i & 3] + db[i];
}

// ---------------------------------------------------------------------------
// Kernel 1: dense projection, K-split in thirds for load balance.
// grid = 331*3 blocks x 256 threads. block = (vb = bid/3, kt = bid%3).
// lane = vocab row (64/block), wave = t (weights wave-uniform -> s_load).
// A-panel chunks (64 rows x 64 k) double-buffered in LDS [k][65].
// part[(kt*4+t)*10+c][v] = partial dot over this block's 256 k's.
// ---------------------------------------------------------------------------
__global__ __launch_bounds__(256) void proj_kernel(
    const float* __restrict__ embed, const float* __restrict__ wt,
    float* __restrict__ part)
{
  const int tid = threadIdx.x;
  const int lane = tid & 63;
  const int wave_t = __builtin_amdgcn_readfirstlane(tid >> 6);
  const int vb = blockIdx.x / 3;
  const int kt = blockIdx.x % 3;
  const int kbase = kt * 256;
  const int vbase = vb * 64;

  __shared__ float A[2][64][65];

  const int srow = tid >> 4;          // 0..15, +16*i -> 0..63
  const int sk4 = (tid & 15) * 4;     // k-quad within chunk

  // stage chunk 0
  {
    float4 v[4];
#pragma unroll
    for (int i = 0; i < 4; ++i) {
      int rg = vbase + srow + i * 16; if (rg >= VOCAB) rg = VOCAB - 1;
      v[i] = *(const float4*)(embed + (size_t)rg * ND + kbase + sk4);
    }
#pragma unroll
    for (int i = 0; i < 4; ++i) {
      const int row = srow + i * 16;
      A[0][sk4 + 0][row] = v[i].x;
      A[0][sk4 + 1][row] = v[i].y;
      A[0][sk4 + 2][row] = v[i].z;
      A[0][sk4 + 3][row] = v[i].w;
    }
  }
  __syncthreads();

  float acc[NC];
#pragma unroll
  for (int c = 0; c < NC; ++c) acc[c] = 0.f;

  for (int ch = 0; ch < 4; ++ch) {
    const int cur = ch & 1;
    // T14: issue next chunk's global loads BEFORE compute
    float4 nxt[4];
    if (ch < 3) {
#pragma unroll
      for (int i = 0; i < 4; ++i) {
        int rg = vbase + srow + i * 16; if (rg >= VOCAB) rg = VOCAB - 1;
        nxt[i] = *(const float4*)(embed + (size_t)rg * ND + kbase + (ch + 1) * 64 + sk4);
      }
    }
    // compute current chunk; weights wave-uniform -> scalar loads
    const float* __restrict__ wrow = wt + wave_t * (ND * NC) + (kbase + ch * 64) * NC;
#pragma unroll 8
    for (int k = 0; k < 64; ++k) {
      const float a = A[cur][k][lane];
#pragma unroll
      for (int c = 0; c < NC; ++c)
        acc[c] = fmaf(a, wrow[k * NC + c], acc[c]);
    }
    // write-late: LDS store of prefetched chunk (vmcnt wait hidden by compute)
    if (ch < 3) {
#pragma unroll
      for (int i = 0; i < 4; ++i) {
        const int row = srow + i * 16;
        A[cur ^ 1][sk4 + 0][row] = nxt[i].x;
        A[cur ^ 1][sk4 + 1][row] = nxt[i].y;
        A[cur ^ 1][sk4 + 2][row] = nxt[i].z;
        A[cur ^ 1][sk4 + 3][row] = nxt[i].w;
      }
    }
    __syncthreads();
  }

  const int vg = vbase + lane;
  if (vg < VOCAB) {
#pragma unroll
    for (int c = 0; c < NC; ++c)
      part[(size_t)((kt * NT + wave_t) * NC + c) * VOCAB + vg] = acc[c];
  }
}

// ---------------------------------------------------------------------------
// Kernel 2: combine 3 K-partials + bias -> log_softmax -> table[c][v][4]
// grid covers 211280 (v,c) pairs; coalesced over v.
// ---------------------------------------------------------------------------
__global__ __launch_bounds__(256) void lsm_kernel(
    const float* __restrict__ part, const float* __restrict__ beff,
    float* __restrict__ table)
{
  const int e = blockIdx.x * 256 + threadIdx.x;
  if (e >= NC * VOCAB) return;
  const int c = e / VOCAB;
  const int v = e - c * VOCAB;

  float s[NT];
#pragma unroll
  for (int t = 0; t < NT; ++t) {
    float acc = beff[c * NT + t];
#pragma unroll
    for (int kt = 0; kt < 3; ++kt)
      acc += part[(size_t)((kt * NT + t) * NC + c) * VOCAB + v];
    s[t] = acc;
  }
  const float m = fmaxf(fmaxf(s[0], s[1]), fmaxf(s[2], s[3]));
  const float sum = __expf(s[0] - m) + __expf(s[1] - m) +
                    __expf(s[2] - m) + __expf(s[3] - m);
  const float lse = m + __logf(sum);
  ((float4*)table)[c * VOCAB + v] =
      make_float4(s[0] - lse, s[1] - lse, s[2] - lse, s[3] - lse);
}

// ---------------------------------------------------------------------------
// Kernel 3: CRF chunk-parallel log-semiring scan + gold, gathering logits
// directly from lsm_table (16 B per token, L2-resident 3.4 MB table).
// ---------------------------------------------------------------------------
__global__ __launch_bounds__(256) void crf_kernel(
    const int* __restrict__ words, const int* __restrict__ target,
    const float* __restrict__ trans, const float* __restrict__ start_s,
    const float* __restrict__ end_s, const float* __restrict__ table,
    const int* __restrict__ corpus, float* __restrict__ out)
{
  const int tid = threadIdx.x;
  const int b = blockIdx.x;
  const int c = tid >> 2;   // chunk 0..63
  const int a = tid & 3;    // basis row

  __shared__ float bufA[64][16];
  __shared__ float bufB[32][16];
  __shared__ float wg[4];
  __shared__ int   wc[4];

  const int cb = corpus[b];
  const float* __restrict__ tab = table + (size_t)cb * VOCAB * NT;
  const int* wb = words + b * NS;
  const int* tb = target + b * NS;

  // ---- gold partials: positions 2*tid, 2*tid+1 ----
  float gp = 0.f; int cp = 0;
#pragma unroll
  for (int q = 0; q < 2; ++q) {
    const int s = tid * 2 + q;
    const int w_s = wb[s];
    if (w_s != 0) {
      const int t = tb[s];
      const float4 lv = *(const float4*)(tab + (size_t)w_s * 4);
      gp += (t == 0) ? lv.x : (t == 1) ? lv.y : (t == 2) ? lv.z : lv.w;
      if (s > 0) gp += trans[tb[s - 1] * 4 + t];
      ++cp;
    }
  }
#pragma unroll
  for (int off = 32; off; off >>= 1) {
    gp += __shfl_xor(gp, off);
    cp += __shfl_xor(cp, off);
  }
  if ((tid & 63) == 0) { wg[tid >> 6] = gp; wc[tid >> 6] = cp; }

  // ---- phase A: chunk recursion ----
  float T[4][4];
#pragma unroll
  for (int i = 0; i < 4; ++i)
#pragma unroll
    for (int j = 0; j < 4; ++j) T[i][j] = trans[i * 4 + j];

  const int s_beg = 1 + c * 8;   // chunks cover s = 1..511
  float4 lv[8]; int wm[8];
#pragma unroll
  for (int q = 0; q < 8; ++q) {
    const int s = s_beg + q;
    const bool in = s < NS;
    wm[q] = in ? wb[s] : 0;
    lv[q] = *(const float4*)(tab + (size_t)wm[q] * 4);
  }

  float v0 = (a == 0) ? 0.f : NEG;
  float v1 = (a == 1) ? 0.f : NEG;
  float v2 = (a == 2) ? 0.f : NEG;
  float v3 = (a == 3) ? 0.f : NEG;
#pragma unroll
  for (int q = 0; q < 8; ++q) {
    if (wm[q] != 0) {
      const float4 l = lv[q];
      float t0, t1, t2, t3, m, sm;
      float n0, n1, n2, n3;
      t0 = v0 + T[0][0]; t1 = v1 + T[1][0]; t2 = v2 + T[2][0]; t3 = v3 + T[3][0];
      m = fmaxf(fmaxf(t0, t1), fmaxf(t2, t3));
      sm = __expf(t0 - m) + __expf(t1 - m) + __expf(t2 - m) + __expf(t3 - m);
      n0 = m + __logf(sm) + l.x;
      t0 = v0 + T[0][1]; t1 = v1 + T[1][1]; t2 = v2 + T[2][1]; t3 = v3 + T[3][1];
      m = fmaxf(fmaxf(t0, t1), fmaxf(t2, t3));
      sm = __expf(t0 - m) + __expf(t1 - m) + __expf(t2 - m) + __expf(t3 - m);
      n1 = m + __logf(sm) + l.y;
      t0 = v0 + T[0][2]; t1 = v1 + T[1][2]; t2 = v2 + T[2][2]; t3 = v3 + T[3][2];
      m = fmaxf(fmaxf(t0, t1), fmaxf(t2, t3));
      sm = __expf(t0 - m) + __expf(t1 - m) + __expf(t2 - m) + __expf(t3 - m);
      n2 = m + __logf(sm) + l.z;
      t0 = v0 + T[0][3]; t1 = v1 + T[1][3]; t2 = v2 + T[2][3]; t3 = v3 + T[3][3];
      m = fmaxf(fmaxf(t0, t1), fmaxf(t2, t3));
      sm = __expf(t0 - m) + __expf(t1 - m) + __expf(t2 - m) + __expf(t3 - m);
      n3 = m + __logf(sm) + l.w;
      v0 = n0; v1 = n1; v2 = n2; v3 = n3;
    }
  }
  bufA[c][a * 4 + 0] = v0;
  bufA[c][a * 4 + 1] = v1;
  bufA[c][a * 4 + 2] = v2;
  bufA[c][a * 4 + 3] = v3;

  // ---- phase B: pairwise tree composition (6 levels) ----
  float* src = &bufA[0][0];
  float* dst = &bufB[0][0];
  for (int n = 64; n > 1; n >>= 1) {
    const int entries = (n >> 1) * 16;
    __syncthreads();
    for (int e = tid; e < entries; e += 256) {
      const int p = e >> 4;
      const int aa = (e >> 2) & 3;
      const int jj = e & 3;
      const float* C1 = src + (2 * p) * 16;
      const float* C2 = src + (2 * p + 1) * 16;
      const float t0 = C1[aa * 4 + 0] + C2[0 * 4 + jj];
      const float t1 = C1[aa * 4 + 1] + C2[1 * 4 + jj];
      const float t2 = C1[aa * 4 + 2] + C2[2 * 4 + jj];
      const float t3 = C1[aa * 4 + 3] + C2[3 * 4 + jj];
      const float m = fmaxf(fmaxf(t0, t1), fmaxf(t2, t3));
      dst[p * 16 + aa * 4 + jj] =
          m + __logf(__expf(t0 - m) + __expf(t1 - m) + __expf(t2 - m) + __expf(t3 - m));
    }
    float* tmp = src; src = dst; dst = tmp;
  }
  __syncthreads();

  if (tid == 0) {
    const float* C = &bufA[0][0];
    const float4 l0 = *(const float4*)(tab + (size_t)wb[0] * 4);
    const float a0 = l0.x + start_s[0];
    const float a1 = l0.y + start_s[1];
    const float a2 = l0.z + start_s[2];
    const float a3 = l0.w + start_s[3];
    float af[4];
#pragma unroll
    for (int j = 0; j < 4; ++j) {
      const float t0 = a0 + C[0 * 4 + j];
      const float t1 = a1 + C[1 * 4 + j];
      const float t2 = a2 + C[2 * 4 + j];
      const float t3 = a3 + C[3 * 4 + j];
      const float m = fmaxf(fmaxf(t0, t1), fmaxf(t2, t3));
      af[j] = m + __logf(__expf(t0 - m) + __expf(t1 - m) + __expf(t2 - m) + __expf(t3 - m));
    }
    const float z0 = af[0] + end_s[0], z1 = af[1] + end_s[1];
    const float z2 = af[2] + end_s[2], z3 = af[3] + end_s[3];
    const float mz = fmaxf(fmaxf(z0, z1), fmaxf(z2, z3));
    const float norm = mz + __logf(__expf(z0 - mz) + __expf(z1 - mz) +
                                   __expf(z2 - mz) + __expf(z3 - mz));

    float gold = wg[0] + wg[1] + wg[2] + wg[3];
    const int cnt = wc[0] + wc[1] + wc[2] + wc[3];
    const int last = (cnt - 1) > 0 ? (cnt - 1) : 0;
    gold += start_s[tb[0]] + end_s[tb[last]];
    out[b] = norm - gold;
  }
}

extern "C" void kernel_launch(void* const* d_in, const int* in_sizes, int n_in,
                              void* d_out, int out_size, void* d_ws, size_t ws_size,
                              hipStream_t stream) {
  const int*   words   = (const int*)d_in[0];
  const int*   target  = (const int*)d_in[1];
  const int*   corpus  = (const int*)d_in[2];
  const float* embed   = (const float*)d_in[3];
  const float* sW      = (const float*)d_in[4];
  const float* sb      = (const float*)d_in[5];
  const float* dA      = (const float*)d_in[6];
  const float* db      = (const float*)d_in[7];
  const float* trans   = (const float*)d_in[8];
  const float* start_s = (const float*)d_in[9];
  const float* end_s   = (const float*)d_in[10];
  float* out = (float*)d_out;

  // ws layout
  float* table = (float*)d_ws;                        // NC*VOCAB*4   = 845,120 f
  float* part  = table + (size_t)NC * VOCAB * NT;     // 12*NC*VOCAB  = 2,535,360 f
  float* wt    = part + (size_t)3 * NT * NC * VOCAB;  // 4*768*10     = 30,720 f
  float* beff  = wt + NT * ND * NC;                   // 40 f

  weff_kernel<<<(NT * ND * NC + 255) / 256, 256, 0, stream>>>(sW, dA, sb, db, wt, beff);
  proj_kernel<<<331 * 3, 256, 0, stream>>>(embed, wt, part);
  lsm_kernel<<<(NC * VOCAB + 255) / 256, 256, 0, stream>>>(part, beff, table);
  crf_kernel<<<NB, 256, 0, stream>>>(words, target, trans, start_s, end_s, table, corpus, out);
}

// Round 5
// 30.507 us; speedup vs baseline: 1.5696x; 1.5696x over previous
//
#include <hip/hip_runtime.h>

#define NB 64
#define NS 512
#define ND 768
#define NT 4
#define NC 10
#define NEG (-1e30f)

// ---------------------------------------------------------------------------
// Kernel 1: fused embedding gather + projection + log_softmax.
// grid = 2048 blocks x 256 threads; 16 tokens per block, 16 lanes per token.
// Block builds W_eff = sW + dA[corpus] (12 KB) in LDS, then lane q of each
// 16-lane group streams its token's row as float4 (256 B coalesced per
// group-instr), weights via broadcast ds_read_b128.
// ---------------------------------------------------------------------------
__global__ __launch_bounds__(256) void logits_kernel(
    const int* __restrict__ words, const int* __restrict__ corpus,
    const float* __restrict__ embed, const float* __restrict__ sW,
    const float* __restrict__ sb, const float* __restrict__ dA,
    const float* __restrict__ db, float* __restrict__ logits)
{
  __shared__ float4 Wl[ND];   // W_eff[d][0..3]
  __shared__ float4 bl;

  const int tid = threadIdx.x;
  const int blk = blockIdx.x;
  const int b = blk >> 5;                                   // 32 blocks/batch
  const int c = __builtin_amdgcn_readfirstlane(corpus[b]);  // uniform

  // stage W_eff into LDS (3 float4 per thread, coalesced)
  const float4* sW4 = (const float4*)sW;
  const float4* dA4 = ((const float4*)dA) + (size_t)c * ND;
#pragma unroll
  for (int k = 0; k < 3; ++k) {
    const int d = tid + k * 256;
    const float4 a = sW4[d];
    const float4 e = dA4[d];
    Wl[d] = make_float4(a.x + e.x, a.y + e.y, a.z + e.z, a.w + e.w);
  }
  if (tid == 0) {
    const float4 a = *(const float4*)sb;
    const float4 e = ((const float4*)db)[c];
    bl = make_float4(a.x + e.x, a.y + e.y, a.z + e.z, a.w + e.w);
  }
  __syncthreads();

  const int lane = tid & 63;
  const int grp  = lane >> 4;          // 4 token-groups per wave
  const int q    = lane & 15;          // lane within group
  const int g    = blk * 16 + (tid >> 6) * 4 + grp;   // global token

  const int word = words[g];
  const float4* __restrict__ row4 = (const float4*)(embed + (size_t)word * ND);

  float a0 = 0.f, a1 = 0.f, a2 = 0.f, a3 = 0.f;
#pragma unroll
  for (int i = 0; i < 12; ++i) {
    const float4 xv = row4[i * 16 + q];        // d = i*64 + q*4 .. +3
    const float4 w0 = Wl[i * 64 + q * 4 + 0];
    const float4 w1 = Wl[i * 64 + q * 4 + 1];
    const float4 w2 = Wl[i * 64 + q * 4 + 2];
    const float4 w3 = Wl[i * 64 + q * 4 + 3];
    a0 = fmaf(xv.x, w0.x, a0); a1 = fmaf(xv.x, w0.y, a1);
    a2 = fmaf(xv.x, w0.z, a2); a3 = fmaf(xv.x, w0.w, a3);
    a0 = fmaf(xv.y, w1.x, a0); a1 = fmaf(xv.y, w1.y, a1);
    a2 = fmaf(xv.y, w1.z, a2); a3 = fmaf(xv.y, w1.w, a3);
    a0 = fmaf(xv.z, w2.x, a0); a1 = fmaf(xv.z, w2.y, a1);
    a2 = fmaf(xv.z, w2.z, a2); a3 = fmaf(xv.z, w2.w, a3);
    a0 = fmaf(xv.w, w3.x, a0); a1 = fmaf(xv.w, w3.y, a1);
    a2 = fmaf(xv.w, w3.z, a2); a3 = fmaf(xv.w, w3.w, a3);
  }

  // 16-lane group reduce (4 levels)
#pragma unroll
  for (int off = 8; off; off >>= 1) {
    a0 += __shfl_xor(a0, off);
    a1 += __shfl_xor(a1, off);
    a2 += __shfl_xor(a2, off);
    a3 += __shfl_xor(a3, off);
  }

  if (q == 0) {
    a0 += bl.x; a1 += bl.y; a2 += bl.z; a3 += bl.w;
    const float m = fmaxf(fmaxf(a0, a1), fmaxf(a2, a3));
    const float sum = __expf(a0 - m) + __expf(a1 - m) +
                      __expf(a2 - m) + __expf(a3 - m);
    const float lse = m + __logf(sum);
    ((float4*)logits)[g] = make_float4(a0 - lse, a1 - lse, a2 - lse, a3 - lse);
  }
}

// ---------------------------------------------------------------------------
// Kernel 2: CRF via chunk-parallel log-semiring scan + fused gold score.
// (unchanged from round 2 — passed with absmax 0.0)
// ---------------------------------------------------------------------------
__global__ __launch_bounds__(256) void crf_kernel(
    const int* __restrict__ words, const int* __restrict__ target,
    const float* __restrict__ trans, const float* __restrict__ start_s,
    const float* __restrict__ end_s, const float* __restrict__ logits,
    float* __restrict__ out)
{
  const int tid = threadIdx.x;
  const int b = blockIdx.x;
  const int c = tid >> 2;   // chunk 0..63
  const int a = tid & 3;    // basis row

  __shared__ float bufA[64][16];
  __shared__ float bufB[32][16];
  __shared__ float wg[4];
  __shared__ int   wc[4];

  const float* lg = logits + (size_t)b * NS * NT;
  const int* wb = words + b * NS;
  const int* tb = target + b * NS;

  // ---- gold partials: positions 2*tid, 2*tid+1 ----
  float gp = 0.f; int cp = 0;
#pragma unroll
  for (int q = 0; q < 2; ++q) {
    const int s = tid * 2 + q;
    if (wb[s] != 0) {
      const int t = tb[s];
      gp += lg[s * 4 + t];
      if (s > 0) gp += trans[tb[s - 1] * 4 + t];
      ++cp;
    }
  }
#pragma unroll
  for (int off = 32; off; off >>= 1) {
    gp += __shfl_xor(gp, off);
    cp += __shfl_xor(cp, off);
  }
  if ((tid & 63) == 0) { wg[tid >> 6] = gp; wc[tid >> 6] = cp; }

  // ---- phase A: chunk recursion ----
  float T[4][4];
#pragma unroll
  for (int i = 0; i < 4; ++i)
#pragma unroll
    for (int j = 0; j < 4; ++j) T[i][j] = trans[i * 4 + j];

  const int s_beg = 1 + c * 8;   // chunks cover s = 1..511
  float4 lv[8]; int wm[8];
#pragma unroll
  for (int q = 0; q < 8; ++q) {
    const int s = s_beg + q;
    const bool in = s < NS;
    wm[q] = in ? wb[s] : 0;
    lv[q] = in ? *(const float4*)(lg + s * 4) : make_float4(0.f, 0.f, 0.f, 0.f);
  }

  float v0 = (a == 0) ? 0.f : NEG;
  float v1 = (a == 1) ? 0.f : NEG;
  float v2 = (a == 2) ? 0.f : NEG;
  float v3 = (a == 3) ? 0.f : NEG;
#pragma unroll
  for (int q = 0; q < 8; ++q) {
    if (wm[q] != 0) {
      const float4 l = lv[q];
      float t0, t1, t2, t3, m, sm;
      float n0, n1, n2, n3;
      t0 = v0 + T[0][0]; t1 = v1 + T[1][0]; t2 = v2 + T[2][0]; t3 = v3 + T[3][0];
      m = fmaxf(fmaxf(t0, t1), fmaxf(t2, t3));
      sm = __expf(t0 - m) + __expf(t1 - m) + __expf(t2 - m) + __expf(t3 - m);
      n0 = m + __logf(sm) + l.x;
      t0 = v0 + T[0][1]; t1 = v1 + T[1][1]; t2 = v2 + T[2][1]; t3 = v3 + T[3][1];
      m = fmaxf(fmaxf(t0, t1), fmaxf(t2, t3));
      sm = __expf(t0 - m) + __expf(t1 - m) + __expf(t2 - m) + __expf(t3 - m);
      n1 = m + __logf(sm) + l.y;
      t0 = v0 + T[0][2]; t1 = v1 + T[1][2]; t2 = v2 + T[2][2]; t3 = v3 + T[3][2];
      m = fmaxf(fmaxf(t0, t1), fmaxf(t2, t3));
      sm = __expf(t0 - m) + __expf(t1 - m) + __expf(t2 - m) + __expf(t3 - m);
      n2 = m + __logf(sm) + l.z;
      t0 = v0 + T[0][3]; t1 = v1 + T[1][3]; t2 = v2 + T[2][3]; t3 = v3 + T[3][3];
      m = fmaxf(fmaxf(t0, t1), fmaxf(t2, t3));
      sm = __expf(t0 - m) + __expf(t1 - m) + __expf(t2 - m) + __expf(t3 - m);
      n3 = m + __logf(sm) + l.w;
      v0 = n0; v1 = n1; v2 = n2; v3 = n3;
    }
  }
  bufA[c][a * 4 + 0] = v0;
  bufA[c][a * 4 + 1] = v1;
  bufA[c][a * 4 + 2] = v2;
  bufA[c][a * 4 + 3] = v3;

  // ---- phase B: pairwise tree composition (6 levels) ----
  float* src = &bufA[0][0];
  float* dst = &bufB[0][0];
  for (int n = 64; n > 1; n >>= 1) {
    const int entries = (n >> 1) * 16;
    __syncthreads();
    for (int e = tid; e < entries; e += 256) {
      const int p = e >> 4;
      const int aa = (e >> 2) & 3;
      const int jj = e & 3;
      const float* C1 = src + (2 * p) * 16;
      const float* C2 = src + (2 * p + 1) * 16;
      const float t0 = C1[aa * 4 + 0] + C2[0 * 4 + jj];
      const float t1 = C1[aa * 4 + 1] + C2[1 * 4 + jj];
      const float t2 = C1[aa * 4 + 2] + C2[2 * 4 + jj];
      const float t3 = C1[aa * 4 + 3] + C2[3 * 4 + jj];
      const float m = fmaxf(fmaxf(t0, t1), fmaxf(t2, t3));
      dst[p * 16 + aa * 4 + jj] =
          m + __logf(__expf(t0 - m) + __expf(t1 - m) + __expf(t2 - m) + __expf(t3 - m));
    }
    float* tmp = src; src = dst; dst = tmp;
  }
  __syncthreads();

  if (tid == 0) {
    const float* C = &bufA[0][0];
    const float4 l0 = *(const float4*)lg;
    const float a0 = l0.x + start_s[0];
    const float a1 = l0.y + start_s[1];
    const float a2 = l0.z + start_s[2];
    const float a3 = l0.w + start_s[3];
    float af[4];
#pragma unroll
    for (int j = 0; j < 4; ++j) {
      const float t0 = a0 + C[0 * 4 + j];
      const float t1 = a1 + C[1 * 4 + j];
      const float t2 = a2 + C[2 * 4 + j];
      const float t3 = a3 + C[3 * 4 + j];
      const float m = fmaxf(fmaxf(t0, t1), fmaxf(t2, t3));
      af[j] = m + __logf(__expf(t0 - m) + __expf(t1 - m) + __expf(t2 - m) + __expf(t3 - m));
    }
    const float z0 = af[0] + end_s[0], z1 = af[1] + end_s[1];
    const float z2 = af[2] + end_s[2], z3 = af[3] + end_s[3];
    const float mz = fmaxf(fmaxf(z0, z1), fmaxf(z2, z3));
    const float norm = mz + __logf(__expf(z0 - mz) + __expf(z1 - mz) +
                                   __expf(z2 - mz) + __expf(z3 - mz));

    float gold = wg[0] + wg[1] + wg[2] + wg[3];
    const int cnt = wc[0] + wc[1] + wc[2] + wc[3];
    const int last = (cnt - 1) > 0 ? (cnt - 1) : 0;
    gold += start_s[tb[0]] + end_s[tb[last]];
    out[b] = norm - gold;
  }
}

extern "C" void kernel_launch(void* const* d_in, const int* in_sizes, int n_in,
                              void* d_out, int out_size, void* d_ws, size_t ws_size,
                              hipStream_t stream) {
  const int*   words   = (const int*)d_in[0];
  const int*   target  = (const int*)d_in[1];
  const int*   corpus  = (const int*)d_in[2];
  const float* embed   = (const float*)d_in[3];
  const float* sW      = (const float*)d_in[4];
  const float* sb      = (const float*)d_in[5];
  const float* dA      = (const float*)d_in[6];
  const float* db      = (const float*)d_in[7];
  const float* trans   = (const float*)d_in[8];
  const float* start_s = (const float*)d_in[9];
  const float* end_s   = (const float*)d_in[10];
  float* out = (float*)d_out;
  float* logits = (float*)d_ws;   // NB*NS*NT floats = 512 KB

  logits_kernel<<<(NB * NS) / 16, 256, 0, stream>>>(words, corpus, embed, sW, sb, dA, db, logits);
  crf_kernel<<<NB, 256, 0, stream>>>(words, target, trans, start_s, end_s, logits, out);
}